// Round 3
// baseline (253.155 us; speedup 1.0000x reference)
//
#include <hip/hip_runtime.h>
#include <math.h>

#define B_ 256
#define N_ 128
#define D_ 128
#define L_ 32
#define E_ 262144
#define PW_ 254          // bitmap words per graph = 8128/32
#define DCAP 96          // per-node neighbor capacity (max deg ~40 expected)

// workspace layout (u32 units)
#define NDEG_OFF 0               // 32768 u32 per-node degree counters
#define BM_OFF   32768           // 65024 u32 pair-target bitmap
#define KLS_OFF  97792           // 256 f32 per-graph KL sums
#define LP_OFF   98048           // 256 f32 per-graph log_prob sums
#define DONE_OFF 98304           // 16 u32 (ticket counter + pad)
#define ADJ_OFF  98320           // 32768*96 u8 CSR neighbor lists (786432 u32)
#define Z_OFF    884752          // 32768*32 f32 latents
#define ZERO_WORDS 98320         // ndeg + bitmap + kls + logp + ticket

// ---------------------------------------------------------------------------
// Per-edge: CSR adjacency build (atomics over 32768 node counters) + bitmap.
__global__ __launch_bounds__(256) void k_build(
    const int* __restrict__ ei, unsigned* __restrict__ ndeg,
    unsigned char* __restrict__ adj, unsigned* __restrict__ bm)
{
    int e = blockIdx.x * 256 + threadIdx.x;
    int src = ei[e], dst = ei[E_ + e];
    unsigned s1 = atomicAdd(&ndeg[src], 1u);
    if (s1 < DCAP) adj[(size_t)src * DCAP + s1] = (unsigned char)(dst & 127);
    unsigned s2 = atomicAdd(&ndeg[dst], 1u);
    if (s2 < DCAP) adj[(size_t)dst * DCAP + s2] = (unsigned char)(src & 127);
    int li = src & 127, lj = dst & 127, g = src >> 7;
    int p = li * (255 - li) / 2 + (lj - li - 1);
    atomicOr(&bm[g * PW_ + (p >> 5)], 1u << (p & 31));
}

// Prefetch helpers as MACROS (no lambdas: round-2's by-ref lambda captures
// made pre-regs addressable -> 214 MB scratch spill; macros keep p0/p1 as
// plain VGPR float4s in straight-line unrolled code).
#define ISSUE_W1(s) do { \
    const float4* gp_ = (const float4*)(W1 + (s) * 2048); \
    p0 = gp_[t]; p1 = gp_[t + 256]; } while (0)

#define ISSUE_WB(ch) do { \
    int r0_ = t >> 4, c0_ = (t & 15) << 2; \
    int r1_ = (t + 256) >> 4, c1_ = ((t + 256) & 15) << 2; \
    int rg0_ = (ch) * 32 + r0_, rg1_ = (ch) * 32 + r1_; \
    p0 = (c0_ < 32) ? *(const float4*)(Wmu + rg0_ * 32 + c0_) \
                    : *(const float4*)(Wls + rg0_ * 32 + c0_ - 32); \
    p1 = (c1_ < 32) ? *(const float4*)(Wmu + rg1_ * 32 + c1_) \
                    : *(const float4*)(Wls + rg1_ * 32 + c1_ - 32); } while (0)

#define COMMIT(buf) do { \
    ((float4*)Ws[buf])[t] = p0; \
    ((float4*)Ws[buf])[t + 256] = p1; } while (0)

// ---------------------------------------------------------------------------
// Fused gather+encoder (round-0 proven structure + register-dbuf W staging).
// W1 = 8 chunks x 16 rows (8 KB), WB = 4 chunks x 32 rows (8 KB), double-
// buffered in Ws[2][2048]. Per chunk: compute(buf) -> commit next chunk
// (regs->LDS) -> issue chunk+2 (global->regs) -> ONE barrier. Every global
// load has a full compute phase in flight before its ds_write. Summation
// order identical to round-0 (bit-exact). LDS = 16896+16384 = 33280 B,
// 4 blk/CU.
__global__ __launch_bounds__(256, 4) void k_encoder(
    const float* __restrict__ x, const unsigned* __restrict__ ndeg,
    const unsigned char* __restrict__ adj,
    const float* __restrict__ W1, const float* __restrict__ b1,
    const float* __restrict__ Wmu, const float* __restrict__ bmu,
    const float* __restrict__ Wls, const float* __restrict__ bls,
    const float* __restrict__ eps,
    float* __restrict__ z, float* __restrict__ kls)
{
    __shared__ float XAs[32 * 132];   // 16896 B; reused as HS after GEMM1
    __shared__ float Ws[2][2048];     // 2 x 8192 B W stage
    int t = threadIdx.x;
    int g = blockIdx.x & 255;         // graph (fixes XCD: g % 8)
    int quar = blockIdx.x >> 8;       // 0..3
    int row0 = g * 128 + quar * 32;
    int rg = t >> 5;                  // 0..7
    int cg = t & 31;                  // 0..31
    int lane = t & 63;

    float4 p0, p1;                    // in-flight W stage (8 VGPR)
    ISSUE_W1(0);                      // stage-0 load hides under the gather

    // ---- phase G: gather 32 XA rows; 2 passes x 16 nodes, 16 thr/node ----
    {
        int nidx = t >> 4;            // 0..15
        int fo = (t & 15) * 8;        // float offset 0..120
        for (int p = 0; p < 2; ++p) {
            int lrow = p * 16 + nidx;
            int gnode = row0 + lrow;
            const float* xr = x + (size_t)gnode * 128 + fo;
            float4 a0 = *(const float4*)xr;
            float4 a1 = *(const float4*)(xr + 4);
            int deg = (int)ndeg[gnode];
            if (deg > DCAP) deg = DCAP;
            const unsigned char* al = adj + (size_t)gnode * DCAP;
            const float* gx = x + (size_t)(gnode & ~127) * 128 + fo;
            int e = 0;
            for (; e + 4 <= deg; e += 4) {
                unsigned pk = *(const unsigned*)(al + e);
                const float* r0 = gx + (pk & 255u) * 128;
                const float* r1 = gx + ((pk >> 8) & 255u) * 128;
                const float* r2 = gx + ((pk >> 16) & 255u) * 128;
                const float* r3 = gx + (pk >> 24) * 128;
                float4 v00 = *(const float4*)r0, v01 = *(const float4*)(r0 + 4);
                float4 v10 = *(const float4*)r1, v11 = *(const float4*)(r1 + 4);
                float4 v20 = *(const float4*)r2, v21 = *(const float4*)(r2 + 4);
                float4 v30 = *(const float4*)r3, v31 = *(const float4*)(r3 + 4);
                a0.x += v00.x + v10.x + v20.x + v30.x;
                a0.y += v00.y + v10.y + v20.y + v30.y;
                a0.z += v00.z + v10.z + v20.z + v30.z;
                a0.w += v00.w + v10.w + v20.w + v30.w;
                a1.x += v01.x + v11.x + v21.x + v31.x;
                a1.y += v01.y + v11.y + v21.y + v31.y;
                a1.z += v01.z + v11.z + v21.z + v31.z;
                a1.w += v01.w + v11.w + v21.w + v31.w;
            }
            for (; e < deg; ++e) {
                const float* r = gx + (unsigned)al[e] * 128;
                float4 v0 = *(const float4*)r, v1 = *(const float4*)(r + 4);
                a0.x += v0.x; a0.y += v0.y; a0.z += v0.z; a0.w += v0.w;
                a1.x += v1.x; a1.y += v1.y; a1.z += v1.z; a1.w += v1.w;
            }
            *(float4*)(XAs + lrow * 132 + fo) = a0;
            *(float4*)(XAs + lrow * 132 + fo + 4) = a1;
        }
    }

    COMMIT(0);                        // stage 0 -> buf0
    ISSUE_W1(1);                      // stage 1 in flight
    __syncthreads();                  // publishes XAs + buf0

    // ---- phase 1: h = relu(XA @ W1 + b1); 8 chunks, reg-dbuf pipeline ----
    float acc[4][4];
    #pragma unroll
    for (int i = 0; i < 4; ++i)
        #pragma unroll
        for (int j = 0; j < 4; ++j) acc[i][j] = 0.f;

    #pragma unroll
    for (int c = 0; c < 8; ++c) {
        const float* Wb = Ws[c & 1];
        #pragma unroll
        for (int k = 0; k < 16; k += 4) {
            float4 av[4], wv[4];
            #pragma unroll
            for (int i = 0; i < 4; ++i)
                av[i] = *(const float4*)(XAs + (4 * rg + i) * 132 + c * 16 + k);
            #pragma unroll
            for (int dk = 0; dk < 4; ++dk)
                wv[dk] = *(const float4*)(Wb + (k + dk) * 128 + 4 * cg);
            #pragma unroll
            for (int i = 0; i < 4; ++i) {
                acc[i][0] += av[i].x * wv[0].x + av[i].y * wv[1].x + av[i].z * wv[2].x + av[i].w * wv[3].x;
                acc[i][1] += av[i].x * wv[0].y + av[i].y * wv[1].y + av[i].z * wv[2].y + av[i].w * wv[3].y;
                acc[i][2] += av[i].x * wv[0].z + av[i].y * wv[1].z + av[i].z * wv[2].z + av[i].w * wv[3].z;
                acc[i][3] += av[i].x * wv[0].w + av[i].y * wv[1].w + av[i].z * wv[2].w + av[i].w * wv[3].w;
            }
        }
        // commit stage c+1 (overwrites buffer last read at stage c-1: safe),
        // then issue stage c+2 (W1 chunks 2..7, then WB chunks 0,1).
        COMMIT((c + 1) & 1);
        if (c < 6)       ISSUE_W1(c + 2);
        else if (c == 6) ISSUE_WB(0);
        else             ISSUE_WB(1);
        __syncthreads();              // publishes stage c+1
    }

    // relu+bias -> HS into same rows (wave-private rows; in-order LDS)
    {
        float4 bb = *(const float4*)(b1 + 4 * cg);
        #pragma unroll
        for (int i = 0; i < 4; ++i) {
            float4 h;
            h.x = fmaxf(acc[i][0] + bb.x, 0.f);
            h.y = fmaxf(acc[i][1] + bb.y, 0.f);
            h.z = fmaxf(acc[i][2] + bb.z, 0.f);
            h.w = fmaxf(acc[i][3] + bb.w, 0.f);
            *(float4*)(XAs + (4 * rg + i) * 132 + 4 * cg) = h;
        }
    }
    // stage 8 (WB0) is in buf0, published by the c==7 barrier above.
    // HS rows are wave-private: same-wave ds write->read needs no barrier.

    // ---- phase 2: [mu|ls] = h @ WB + bias; 4 chunks, reg-dbuf pipeline ----
    float a3[4][2];
    #pragma unroll
    for (int i = 0; i < 4; ++i) { a3[i][0] = 0.f; a3[i][1] = 0.f; }

    #pragma unroll
    for (int c2 = 0; c2 < 4; ++c2) {
        const float* Wb = Ws[c2 & 1];
        #pragma unroll
        for (int k = 0; k < 32; k += 4) {
            float4 av[4];
            float2 wv[4];
            #pragma unroll
            for (int i = 0; i < 4; ++i)
                av[i] = *(const float4*)(XAs + (4 * rg + i) * 132 + c2 * 32 + k);
            #pragma unroll
            for (int dk = 0; dk < 4; ++dk)
                wv[dk] = *(const float2*)(Wb + (k + dk) * 64 + 2 * cg);
            #pragma unroll
            for (int i = 0; i < 4; ++i) {
                a3[i][0] += av[i].x * wv[0].x + av[i].y * wv[1].x + av[i].z * wv[2].x + av[i].w * wv[3].x;
                a3[i][1] += av[i].x * wv[0].y + av[i].y * wv[1].y + av[i].z * wv[2].y + av[i].w * wv[3].y;
            }
        }
        if (c2 < 3) {
            COMMIT((c2 + 1) & 1);     // stage 9+c2
            if (c2 < 2) ISSUE_WB(2 + c2);
            __syncthreads();          // publishes stage 9+c2
        }
    }
    {
        float2 bv = (cg < 16) ? *(const float2*)(bmu + 2 * cg)
                              : *(const float2*)(bls + 2 * cg - 32);
        #pragma unroll
        for (int i = 0; i < 4; ++i) { a3[i][0] += bv.x; a3[i][1] += bv.y; }
    }

    // exchange mu<->ls with partner lane (cg ^ 16)
    float o3[4][2];
    #pragma unroll
    for (int i = 0; i < 4; ++i) {
        o3[i][0] = __shfl_xor(a3[i][0], 16);
        o3[i][1] = __shfl_xor(a3[i][1], 16);
    }

    // ---- phase 3: z = mu + exp(ls)*eps, KL; wave shfl-reduce, 1 atomic ----
    float klsum = 0.f;
    if (cg < 16) {                    // this lane holds mu; partner held ls
        int lo = cg;
        #pragma unroll
        for (int i = 0; i < 4; ++i) {
            int rowg = row0 + 4 * rg + i;
            float mu0 = a3[i][0], mu1 = a3[i][1];
            float ls0 = o3[i][0], ls1 = o3[i][1];
            float2 ev = *(const float2*)(eps + (size_t)rowg * 32 + 2 * lo);
            float s0 = __expf(ls0), s1 = __expf(ls1);
            float2 zv = make_float2(mu0 + s0 * ev.x, mu1 + s1 * ev.y);
            *(float2*)(z + (size_t)rowg * 32 + 2 * lo) = zv;
            klsum += s0 * s0 + mu0 * mu0 - 1.f - 2.f * ls0
                   + s1 * s1 + mu1 * mu1 - 1.f - 2.f * ls1;
        }
    }
    #pragma unroll
    for (int off = 32; off > 0; off >>= 1) klsum += __shfl_xor(klsum, off);
    if (lane == 0) atomicAdd(&kls[g], 0.5f * klsum);
}

// ---------------------------------------------------------------------------
// Decoder: round-0 proven body (scalar zT staging) + last-block ticket that
// folds the final ELBO reduction in (saves the k_finalize launch). The
// __syncthreads before the ticket drains this block's logp atomics
// (compiler emits vmcnt(0) before s_barrier); AGENT-scope loads read the
// coherent point.
__global__ __launch_bounds__(256) void k_decoder(
    const float* __restrict__ z, const unsigned* __restrict__ bitmap,
    float* __restrict__ logp, const float* __restrict__ kls,
    unsigned* __restrict__ done, float* __restrict__ out)
{
    __shared__ float zT[32 * 132];
    __shared__ unsigned bm[PW_];
    __shared__ unsigned lastflag;
    int b = blockIdx.x & 255, quar = blockIdx.x >> 8, t = threadIdx.x;

    #pragma unroll
    for (int i = 0; i < 16; ++i) {
        int c = t + i * 256;
        int n = c >> 5, l = c & 31;
        zT[l * 132 + n] = z[((size_t)b * N_ + n) * L_ + l];
    }
    if (t < PW_) bm[t] = bitmap[b * PW_ + t];
    __syncthreads();

    int i0 = quar * 32 + ((t >> 5) << 2);
    int j0 = (t & 31) << 2;
    float gacc[4][4];
    #pragma unroll
    for (int a = 0; a < 4; ++a)
        #pragma unroll
        for (int c = 0; c < 4; ++c) gacc[a][c] = 0.f;

    #pragma unroll 4
    for (int l = 0; l < 32; ++l) {
        float4 a0 = *(const float4*)(zT + l * 132 + i0);
        float4 b0 = *(const float4*)(zT + l * 132 + j0);
        float za[4] = {a0.x, a0.y, a0.z, a0.w};
        float zb[4] = {b0.x, b0.y, b0.z, b0.w};
        #pragma unroll
        for (int a = 0; a < 4; ++a)
            #pragma unroll
            for (int c = 0; c < 4; ++c) gacc[a][c] += za[a] * zb[c];
    }

    float sum = 0.f;
    #pragma unroll
    for (int a = 0; a < 4; ++a) {
        int i = i0 + a;
        #pragma unroll
        for (int c = 0; c < 4; ++c) {
            int j = j0 + c;
            if (j > i) {
                float lg = gacc[a][c];
                int p = i * (255 - i) / 2 + (j - i - 1);
                unsigned bit = (bm[p >> 5] >> (p & 31)) & 1u;
                float sp = __logf(1.f + __expf(-fabsf(lg))) + fmaxf(lg, 0.f);
                sum += bit ? (lg - sp) : (-sp);
            }
        }
    }
    #pragma unroll
    for (int off = 32; off > 0; off >>= 1) sum += __shfl_xor(sum, off);
    if ((t & 63) == 0) atomicAdd(&logp[b], sum);

    // ---- last-block-done: final ELBO reduction
    __syncthreads();                  // drains this block's atomics (vmcnt)
    if (t == 0) {
        unsigned prev = atomicAdd(done, 1u);
        lastflag = (prev == 4u * B_ - 1u) ? 1u : 0u;
    }
    __syncthreads();
    if (lastflag) {
        float v = __hip_atomic_load(&logp[t], __ATOMIC_RELAXED, __HIP_MEMORY_SCOPE_AGENT)
                - __hip_atomic_load(&kls[t],  __ATOMIC_RELAXED, __HIP_MEMORY_SCOPE_AGENT);
        zT[t] = v;
        __syncthreads();
        for (int s = 128; s > 0; s >>= 1) {
            if (t < s) zT[t] += zT[t + s];
            __syncthreads();
        }
        if (t == 0) out[0] = -zT[0] * (1.0f / 256.0f);
    }
}

// ---------------------------------------------------------------------------
extern "C" void kernel_launch(void* const* d_in, const int* in_sizes, int n_in,
                              void* d_out, int out_size, void* d_ws, size_t ws_size,
                              hipStream_t stream) {
    const float* x   = (const float*)d_in[0];
    const int*   ei  = (const int*)d_in[1];
    // d_in[2] = batch (unused; block-contiguous layout known)
    const float* eps = (const float*)d_in[3];
    const float* W1  = (const float*)d_in[4];
    const float* b1  = (const float*)d_in[5];
    const float* Wmu = (const float*)d_in[6];
    const float* bmu = (const float*)d_in[7];
    const float* Wls = (const float*)d_in[8];
    const float* bls = (const float*)d_in[9];

    unsigned* wsw = (unsigned*)d_ws;
    unsigned*      ndeg = wsw + NDEG_OFF;
    unsigned*      bm   = wsw + BM_OFF;
    float*         kls  = (float*)(wsw + KLS_OFF);
    float*         logp = (float*)(wsw + LP_OFF);
    unsigned*      done = wsw + DONE_OFF;
    unsigned char* adj  = (unsigned char*)(wsw + ADJ_OFF);
    float*         z    = (float*)(wsw + Z_OFF);

    hipMemsetAsync(d_ws, 0, ZERO_WORDS * sizeof(unsigned), stream);

    k_build   <<<E_ / 256, 256, 0, stream>>>(ei, ndeg, adj, bm);
    k_encoder <<<1024, 256, 0, stream>>>(x, ndeg, adj, W1, b1, Wmu, bmu,
                                         Wls, bls, eps, z, kls);
    k_decoder <<<4 * B_, 256, 0, stream>>>(z, bm, logp, kls, done, (float*)d_out);
}

// Round 4
// 184.545 us; speedup vs baseline: 1.3718x; 1.3718x over previous
//
#include <hip/hip_runtime.h>
#include <math.h>

#define B_ 256
#define N_ 128
#define D_ 128
#define L_ 32
#define E_ 262144
#define PW_ 254          // bitmap words per graph = 8128/32
#define DCAP 96          // per-node neighbor capacity (max deg ~40 expected)

// workspace layout (u32 units) — round-0 proven layout
#define NDEG_OFF 0               // 32768 u32 per-node degree counters
#define BM_OFF   32768           // 65024 u32 pair-target bitmap
#define KLS_OFF  97792           // 256 f32 per-graph KL sums
#define LP_OFF   98048           // 256 f32 per-graph log_prob sums
#define ADJ_OFF  98304           // 32768*96 u8 CSR neighbor lists (786432 u32)
#define Z_OFF    884736          // 32768*32 f32 latents
#define ZERO_WORDS 98304         // ndeg + bitmap + kls + logp

// ---------------------------------------------------------------------------
// Per-edge: CSR adjacency build (atomics over 32768 node counters) + bitmap.
__global__ __launch_bounds__(256) void k_build(
    const int* __restrict__ ei, unsigned* __restrict__ ndeg,
    unsigned char* __restrict__ adj, unsigned* __restrict__ bm)
{
    int e = blockIdx.x * 256 + threadIdx.x;
    int src = ei[e], dst = ei[E_ + e];
    unsigned s1 = atomicAdd(&ndeg[src], 1u);
    if (s1 < DCAP) adj[(size_t)src * DCAP + s1] = (unsigned char)(dst & 127);
    unsigned s2 = atomicAdd(&ndeg[dst], 1u);
    if (s2 < DCAP) adj[(size_t)dst * DCAP + s2] = (unsigned char)(src & 127);
    int li = src & 127, lj = dst & 127, g = src >> 7;
    int p = li * (255 - li) / 2 + (lj - li - 1);
    atomicOr(&bm[g * PW_ + (p >> 5)], 1u << (p & 31));
}

// ---------------------------------------------------------------------------
// Fused gather+encoder, round-11: 64-row blocks (grid 512, 2 blocks/graph),
// per-thread tile R=8 x C=4. LDS reads per 4-k-chunk: 12 b128 per 128 FMA
// vs round-0's 8 per 64 (-25% on the LDS-read pipe, which is the measured
// bottleneck: ~33us of per-CU ds_read vs ~15us VALU). W staging amortizes
// 2x (512 blocks x 96 KB from L2). Staging is the round-0 direct
// global->LDS pattern — NO register prefetch (rounds 2-3: any reg-held W
// stage gets software-pipelined by the compiler into a 200+ MB scratch
// spill). Per-acc k-order unchanged -> numerics identical to round-0.
// LDS = 33792 (XAs) + 16384 (Ws) = 50176 B; grid 512 -> 2 blocks/CU.
__global__ __launch_bounds__(256, 2) void k_encoder(
    const float* __restrict__ x, const unsigned* __restrict__ ndeg,
    const unsigned char* __restrict__ adj,
    const float* __restrict__ W1, const float* __restrict__ b1,
    const float* __restrict__ Wmu, const float* __restrict__ bmu,
    const float* __restrict__ Wls, const float* __restrict__ bls,
    const float* __restrict__ eps,
    float* __restrict__ z, float* __restrict__ kls)
{
    __shared__ float XAs[64 * 132];   // 33792 B; reused as HS after GEMM1
    __shared__ float Ws[4096];        // 16384 B; W1 k-quarter / WB k-half
    int t = threadIdx.x;
    int g = blockIdx.x & 255;         // graph (fixes XCD: g % 8)
    int half = blockIdx.x >> 8;       // 0..1
    int row0 = g * 128 + half * 64;
    int rg = t >> 5;                  // 0..7 (8 rows each)
    int cg = t & 31;                  // 0..31 (4 cols each)
    int lane = t & 63;

    // ---- phase G: gather 64 XA rows; 4 passes x 16 nodes, 16 thr/node ----
    {
        int nidx = t >> 4;            // 0..15
        int fo = (t & 15) * 8;        // float offset 0..120
        for (int p = 0; p < 4; ++p) {
            int lrow = p * 16 + nidx;
            int gnode = row0 + lrow;
            const float* xr = x + (size_t)gnode * 128 + fo;
            float4 a0 = *(const float4*)xr;
            float4 a1 = *(const float4*)(xr + 4);
            int deg = (int)ndeg[gnode];
            if (deg > DCAP) deg = DCAP;
            const unsigned char* al = adj + (size_t)gnode * DCAP;
            const float* gx = x + (size_t)(gnode & ~127) * 128 + fo;
            int e = 0;
            for (; e + 4 <= deg; e += 4) {
                unsigned pk = *(const unsigned*)(al + e);
                const float* r0 = gx + (pk & 255u) * 128;
                const float* r1 = gx + ((pk >> 8) & 255u) * 128;
                const float* r2 = gx + ((pk >> 16) & 255u) * 128;
                const float* r3 = gx + (pk >> 24) * 128;
                float4 v00 = *(const float4*)r0, v01 = *(const float4*)(r0 + 4);
                float4 v10 = *(const float4*)r1, v11 = *(const float4*)(r1 + 4);
                float4 v20 = *(const float4*)r2, v21 = *(const float4*)(r2 + 4);
                float4 v30 = *(const float4*)r3, v31 = *(const float4*)(r3 + 4);
                a0.x += v00.x + v10.x + v20.x + v30.x;
                a0.y += v00.y + v10.y + v20.y + v30.y;
                a0.z += v00.z + v10.z + v20.z + v30.z;
                a0.w += v00.w + v10.w + v20.w + v30.w;
                a1.x += v01.x + v11.x + v21.x + v31.x;
                a1.y += v01.y + v11.y + v21.y + v31.y;
                a1.z += v01.z + v11.z + v21.z + v31.z;
                a1.w += v01.w + v11.w + v21.w + v31.w;
            }
            for (; e < deg; ++e) {
                const float* r = gx + (unsigned)al[e] * 128;
                float4 v0 = *(const float4*)r, v1 = *(const float4*)(r + 4);
                a0.x += v0.x; a0.y += v0.y; a0.z += v0.z; a0.w += v0.w;
                a1.x += v1.x; a1.y += v1.y; a1.z += v1.z; a1.w += v1.w;
            }
            *(float4*)(XAs + lrow * 132 + fo) = a0;
            *(float4*)(XAs + lrow * 132 + fo + 4) = a1;
        }
    }
    __syncthreads();

    // ---- phase 1: h = relu(XA @ W1 + b1), W1 in 4 K-quarters ----
    float acc[8][4];
    #pragma unroll
    for (int i = 0; i < 8; ++i)
        #pragma unroll
        for (int j = 0; j < 4; ++j) acc[i][j] = 0.f;

    for (int kq = 0; kq < 4; ++kq) {
        if (kq) __syncthreads();
        #pragma unroll
        for (int i = 0; i < 4; ++i) {
            int c = t + i * 256;      // 1024 float4 = 32x128 W1 rows
            ((float4*)Ws)[c] = ((const float4*)(W1 + kq * 4096))[c];
        }
        __syncthreads();
        #pragma unroll 2
        for (int k = 0; k < 32; k += 4) {
            float4 av[8], wv[4];
            #pragma unroll
            for (int i = 0; i < 8; ++i)
                av[i] = *(const float4*)(XAs + (8 * rg + i) * 132 + kq * 32 + k);
            #pragma unroll
            for (int dk = 0; dk < 4; ++dk)
                wv[dk] = *(const float4*)(Ws + (k + dk) * 128 + 4 * cg);
            #pragma unroll
            for (int i = 0; i < 8; ++i) {
                acc[i][0] += av[i].x * wv[0].x + av[i].y * wv[1].x + av[i].z * wv[2].x + av[i].w * wv[3].x;
                acc[i][1] += av[i].x * wv[0].y + av[i].y * wv[1].y + av[i].z * wv[2].y + av[i].w * wv[3].y;
                acc[i][2] += av[i].x * wv[0].z + av[i].y * wv[1].z + av[i].z * wv[2].z + av[i].w * wv[3].z;
                acc[i][3] += av[i].x * wv[0].w + av[i].y * wv[1].w + av[i].z * wv[2].w + av[i].w * wv[3].w;
            }
        }
    }
    __syncthreads();                  // all XAs reads done -> reuse as HS

    {
        float4 bb = *(const float4*)(b1 + 4 * cg);
        #pragma unroll
        for (int i = 0; i < 8; ++i) {
            float4 h;
            h.x = fmaxf(acc[i][0] + bb.x, 0.f);
            h.y = fmaxf(acc[i][1] + bb.y, 0.f);
            h.z = fmaxf(acc[i][2] + bb.z, 0.f);
            h.w = fmaxf(acc[i][3] + bb.w, 0.f);
            *(float4*)(XAs + (8 * rg + i) * 132 + 4 * cg) = h;
        }
    }

    // ---- phase 2: [mu|ls] = h @ WB + bias, WB in 2 K-halves ----
    float a3[8][2];
    #pragma unroll
    for (int i = 0; i < 8; ++i) { a3[i][0] = 0.f; a3[i][1] = 0.f; }

    for (int kh = 0; kh < 2; ++kh) {
        __syncthreads();              // HS visible (kh=0) / prior Ws reads done
        #pragma unroll
        for (int i = 0; i < 4; ++i) {
            int c = t + i * 256;      // 1024 float4 = 64 rows x 64 cols
            int row = c >> 4, col4 = (c & 15) << 2;
            int rowg = kh * 64 + row;
            float4 v = (col4 < 32) ? *(const float4*)(Wmu + rowg * 32 + col4)
                                   : *(const float4*)(Wls + rowg * 32 + col4 - 32);
            *(float4*)(Ws + row * 64 + col4) = v;
        }
        __syncthreads();
        #pragma unroll 2
        for (int k = 0; k < 64; k += 4) {
            float4 av[8];
            float2 wv[4];
            #pragma unroll
            for (int i = 0; i < 8; ++i)
                av[i] = *(const float4*)(XAs + (8 * rg + i) * 132 + kh * 64 + k);
            #pragma unroll
            for (int dk = 0; dk < 4; ++dk)
                wv[dk] = *(const float2*)(Ws + (k + dk) * 64 + 2 * cg);
            #pragma unroll
            for (int i = 0; i < 8; ++i) {
                a3[i][0] += av[i].x * wv[0].x + av[i].y * wv[1].x + av[i].z * wv[2].x + av[i].w * wv[3].x;
                a3[i][1] += av[i].x * wv[0].y + av[i].y * wv[1].y + av[i].z * wv[2].y + av[i].w * wv[3].y;
            }
        }
    }
    {
        float2 bv = (cg < 16) ? *(const float2*)(bmu + 2 * cg)
                              : *(const float2*)(bls + 2 * cg - 32);
        #pragma unroll
        for (int i = 0; i < 8; ++i) { a3[i][0] += bv.x; a3[i][1] += bv.y; }
    }

    // exchange mu<->ls with partner lane (cg ^ 16)
    float o3[8][2];
    #pragma unroll
    for (int i = 0; i < 8; ++i) {
        o3[i][0] = __shfl_xor(a3[i][0], 16);
        o3[i][1] = __shfl_xor(a3[i][1], 16);
    }

    // ---- phase 3: z = mu + exp(ls)*eps, KL; wave shfl-reduce, 1 atomic ----
    float klsum = 0.f;
    if (cg < 16) {                    // this lane holds mu; partner held ls
        int lo = cg;
        #pragma unroll
        for (int i = 0; i < 8; ++i) {
            int rowg = row0 + 8 * rg + i;
            float mu0 = a3[i][0], mu1 = a3[i][1];
            float ls0 = o3[i][0], ls1 = o3[i][1];
            float2 ev = *(const float2*)(eps + (size_t)rowg * 32 + 2 * lo);
            float s0 = __expf(ls0), s1 = __expf(ls1);
            float2 zv = make_float2(mu0 + s0 * ev.x, mu1 + s1 * ev.y);
            *(float2*)(z + (size_t)rowg * 32 + 2 * lo) = zv;
            klsum += s0 * s0 + mu0 * mu0 - 1.f - 2.f * ls0
                   + s1 * s1 + mu1 * mu1 - 1.f - 2.f * ls1;
        }
    }
    #pragma unroll
    for (int off = 32; off > 0; off >>= 1) klsum += __shfl_xor(klsum, off);
    if (lane == 0) atomicAdd(&kls[g], 0.5f * klsum);
}

// ---------------------------------------------------------------------------
// Decoder: round-0 proven body (4 blocks/graph, scalar zT staging,
// shfl-reduce + one atomic per wave, fast-math softplus).
__global__ __launch_bounds__(256) void k_decoder(
    const float* __restrict__ z, const unsigned* __restrict__ bitmap,
    float* __restrict__ logp)
{
    __shared__ float zT[32 * 132];
    __shared__ unsigned bm[PW_];
    int b = blockIdx.x & 255, quar = blockIdx.x >> 8, t = threadIdx.x;

    #pragma unroll
    for (int i = 0; i < 16; ++i) {
        int c = t + i * 256;
        int n = c >> 5, l = c & 31;
        zT[l * 132 + n] = z[((size_t)b * N_ + n) * L_ + l];
    }
    if (t < PW_) bm[t] = bitmap[b * PW_ + t];
    __syncthreads();

    int i0 = quar * 32 + ((t >> 5) << 2);
    int j0 = (t & 31) << 2;
    float g[4][4];
    #pragma unroll
    for (int a = 0; a < 4; ++a)
        #pragma unroll
        for (int c = 0; c < 4; ++c) g[a][c] = 0.f;

    #pragma unroll 4
    for (int l = 0; l < 32; ++l) {
        float4 a0 = *(const float4*)(zT + l * 132 + i0);
        float4 b0 = *(const float4*)(zT + l * 132 + j0);
        float za[4] = {a0.x, a0.y, a0.z, a0.w};
        float zb[4] = {b0.x, b0.y, b0.z, b0.w};
        #pragma unroll
        for (int a = 0; a < 4; ++a)
            #pragma unroll
            for (int c = 0; c < 4; ++c) g[a][c] += za[a] * zb[c];
    }

    float sum = 0.f;
    #pragma unroll
    for (int a = 0; a < 4; ++a) {
        int i = i0 + a;
        #pragma unroll
        for (int c = 0; c < 4; ++c) {
            int j = j0 + c;
            if (j > i) {
                float lg = g[a][c];
                int p = i * (255 - i) / 2 + (j - i - 1);
                unsigned bit = (bm[p >> 5] >> (p & 31)) & 1u;
                float sp = __logf(1.f + __expf(-fabsf(lg))) + fmaxf(lg, 0.f);
                sum += bit ? (lg - sp) : (-sp);
            }
        }
    }
    #pragma unroll
    for (int off = 32; off > 0; off >>= 1) sum += __shfl_xor(sum, off);
    if ((t & 63) == 0) atomicAdd(&logp[b], sum);
}

// ---------------------------------------------------------------------------
__global__ __launch_bounds__(256) void k_finalize(
    const float* __restrict__ kls, const float* __restrict__ logp,
    float* __restrict__ out)
{
    __shared__ float RED[256];
    int t = threadIdx.x;
    RED[t] = logp[t] - kls[t];
    __syncthreads();
    for (int s = 128; s > 0; s >>= 1) {
        if (t < s) RED[t] += RED[t + s];
        __syncthreads();
    }
    if (t == 0) out[0] = -RED[0] * (1.0f / 256.0f);
}

// ---------------------------------------------------------------------------
extern "C" void kernel_launch(void* const* d_in, const int* in_sizes, int n_in,
                              void* d_out, int out_size, void* d_ws, size_t ws_size,
                              hipStream_t stream) {
    const float* x   = (const float*)d_in[0];
    const int*   ei  = (const int*)d_in[1];
    // d_in[2] = batch (unused; block-contiguous layout known)
    const float* eps = (const float*)d_in[3];
    const float* W1  = (const float*)d_in[4];
    const float* b1  = (const float*)d_in[5];
    const float* Wmu = (const float*)d_in[6];
    const float* bmu = (const float*)d_in[7];
    const float* Wls = (const float*)d_in[8];
    const float* bls = (const float*)d_in[9];

    unsigned* wsw = (unsigned*)d_ws;
    unsigned*      ndeg = wsw + NDEG_OFF;
    unsigned*      bm   = wsw + BM_OFF;
    float*         kls  = (float*)(wsw + KLS_OFF);
    float*         logp = (float*)(wsw + LP_OFF);
    unsigned char* adj  = (unsigned char*)(wsw + ADJ_OFF);
    float*         z    = (float*)(wsw + Z_OFF);

    hipMemsetAsync(d_ws, 0, ZERO_WORDS * sizeof(unsigned), stream);

    k_build   <<<E_ / 256, 256, 0, stream>>>(ei, ndeg, adj, bm);
    k_encoder <<<512, 256, 0, stream>>>(x, ndeg, adj, W1, b1, Wmu, bmu,
                                        Wls, bls, eps, z, kls);
    k_decoder <<<4 * B_, 256, 0, stream>>>(z, bm, logp);
    k_finalize<<<1, 256, 0, stream>>>(kls, logp, (float*)d_out);
}